// Round 3
// baseline (396.065 us; speedup 1.0000x reference)
//
#include <hip/hip_runtime.h>
#include <hip/hip_bf16.h>
#include <math.h>

#define D_DIM 1024
#define A_DIM 256
#define E_NUM 16

typedef __attribute__((ext_vector_type(8))) short short8;   // 8 bf16 (4 VGPRs)
typedef __attribute__((ext_vector_type(4))) float f32x4;    // MFMA acc

__device__ __forceinline__ short f2bs(float x) {
    __hip_bfloat16 h = __float2bfloat16(x);   // RNE
    return __builtin_bit_cast(short, h);
}
__device__ __forceinline__ float bs2f(short s) {
    __hip_bfloat16 h = __builtin_bit_cast(__hip_bfloat16, s);
    return __bfloat162float(h);
}
__device__ __forceinline__ float gelu_exact(float x) {
    return 0.5f * x * (1.0f + erff(x * 0.70710678118654752f));
}
// async global->LDS, 16B per lane; LDS dest must be wave-uniform base + lane*16
__device__ __forceinline__ void gload_lds16(const void* g, void* l) {
    __builtin_amdgcn_global_load_lds(
        (const __attribute__((address_space(1))) void*)g,
        (__attribute__((address_space(3))) void*)l, 16, 0, 0);
}
__device__ __forceinline__ short8 pack8(float4 u, float4 v) {
    short8 pk;
    pk[0] = f2bs(u.x); pk[1] = f2bs(u.y); pk[2] = f2bs(u.z); pk[3] = f2bs(u.w);
    pk[4] = f2bs(v.x); pk[5] = f2bs(v.y); pk[6] = f2bs(v.z); pk[7] = f2bs(v.w);
    return pk;
}

// ---------------------------------------------------------------------------
// cast: weights only (X consumed fp32 directly by the fused GEMM kernel).
// ---------------------------------------------------------------------------
__global__ __launch_bounds__(256) void k_cast_w(
    const float* __restrict__ Wd, const float* __restrict__ Wu,
    const float* __restrict__ eW,
    short* __restrict__ WdB, short* __restrict__ WuB, short* __restrict__ eWB)
{
    unsigned i = blockIdx.x * 256 + threadIdx.x;
    if (i < 131072) {
        const float4* s = (const float4*)eW;
        ((short8*)eWB)[i] = pack8(s[2 * (size_t)i], s[2 * (size_t)i + 1]);
    } else if (i < 163840) {
        unsigned j = i - 131072;
        const float4* s = (const float4*)Wd;
        ((short8*)WdB)[j] = pack8(s[2 * (size_t)j], s[2 * (size_t)j + 1]);
    } else {
        unsigned j = i - 163840;
        const float4* s = (const float4*)Wu;
        ((short8*)WuB)[j] = pack8(s[2 * (size_t)j], s[2 * (size_t)j + 1]);
    }
}

// ---------------------------------------------------------------------------
// Fused down-proj + GELU + expert GEMM.
// T14 async A-stage: X loads for k-step kt+1 issue BEFORE MFMA(kt); the
// cvt+ds_write happens after the barrier (HBM latency hides under MFMA).
// B stays gload_lds DMA (fire-and-forget, no result VGPRs) with the
// both-sides involution swizzle (source col ^, read col ^) from round 2.
// ---------------------------------------------------------------------------
__global__ __launch_bounds__(256, 2) void k_down_expert(
    const float* __restrict__ X, const short* __restrict__ WdB,
    const float* __restrict__ bd, const short* __restrict__ eWB,
    const float* __restrict__ eb, const float* __restrict__ emb,
    const int* __restrict__ domain_id, short* __restrict__ H2)
{
    __shared__ short As[64][72];    // reg-staged: +8 pad legal
    __shared__ short Bs[256][64];   // gload_lds dest: linear; source pre-swizzled
    __shared__ short Hs[64][264];   // H1 panel, +8 pad
    const int tid  = threadIdx.x;
    const int lane = tid & 63;
    const int w    = tid >> 6;          // 0..3 = n-split
    const int quad = lane >> 4, cid = lane & 15;
    const int m0 = blockIdx.x * 64;

    const int samp = m0 >> 10;
    const int id = domain_id[samp];
    const bool valid = (id >= 0) && (id < E_NUM);
    const int idc = id < 0 ? 0 : (id > E_NUM - 1 ? E_NUM - 1 : id);

    f32x4 acc[4][4];
    #pragma unroll
    for (int i = 0; i < 4; i++)
        #pragma unroll
        for (int j = 0; j < 4; j++) acc[i][j] = (f32x4)(0.f);

    // ---- GEMM1 prologue: stage kt=0 -------------------------------------
    #pragma unroll
    for (int p = 0; p < 8; p++) {
        int jj = tid + p * 256;
        int r = jj >> 3;
        int cg = (((jj & 7) ^ (r & 7)) * 8);   // swizzled source col
        int cl = (jj & 7) * 8;                 // linear LDS col
        gload_lds16(WdB + (size_t)r * D_DIM + cg, &Bs[r][cl]);
    }
    #pragma unroll
    for (int p = 0; p < 2; p++) {
        int jj = tid + p * 256;
        int r = jj >> 3, c = (jj & 7) * 8;
        const float4* src = (const float4*)(X + (size_t)(m0 + r) * D_DIM + c);
        *(short8*)&As[r][c] = pack8(src[0], src[1]);
    }
    __syncthreads();

    // ---- GEMM1 main loop: K=1024, k-step 64 -----------------------------
    for (int kt = 0; kt < D_DIM; kt += 64) {
        const bool more = (kt + 64) < D_DIM;
        // T14 issue-early: next A tile into regs, fire before MFMA
        float4 ap00, ap01, ap10, ap11;
        if (more) {
            int jj0 = tid, r0 = jj0 >> 3, c0 = (jj0 & 7) * 8;
            const float4* s0 = (const float4*)(X + (size_t)(m0 + r0) * D_DIM + kt + 64 + c0);
            ap00 = s0[0]; ap01 = s0[1];
            int jj1 = tid + 256, r1 = jj1 >> 3, c1 = (jj1 & 7) * 8;
            const float4* s1 = (const float4*)(X + (size_t)(m0 + r1) * D_DIM + kt + 64 + c1);
            ap10 = s1[0]; ap11 = s1[1];
        }
        #pragma unroll
        for (int kk = 0; kk < 2; kk++) {
            short8 a[4], b[4];
            #pragma unroll
            for (int i = 0; i < 4; i++)
                a[i] = *(const short8*)&As[i * 16 + cid][kk * 32 + quad * 8];
            #pragma unroll
            for (int j = 0; j < 4; j++)
                b[j] = *(const short8*)&Bs[w * 64 + j * 16 + cid]
                                         [(kk * 32 + quad * 8) ^ ((cid & 7) * 8)];
            #pragma unroll
            for (int i = 0; i < 4; i++)
                #pragma unroll
                for (int j = 0; j < 4; j++)
                    acc[i][j] = __builtin_amdgcn_mfma_f32_16x16x32_bf16(
                        a[i], b[j], acc[i][j], 0, 0, 0);
        }
        __syncthreads();                 // all waves done reading stage kt
        if (more) {
            #pragma unroll
            for (int p = 0; p < 8; p++) {
                int jj = tid + p * 256;
                int r = jj >> 3;
                int cg = (((jj & 7) ^ (r & 7)) * 8);
                int cl = (jj & 7) * 8;
                gload_lds16(WdB + (size_t)r * D_DIM + kt + 64 + cg, &Bs[r][cl]);
            }
            {
                int jj0 = tid, r0 = jj0 >> 3, c0 = (jj0 & 7) * 8;
                *(short8*)&As[r0][c0] = pack8(ap00, ap01);
                int jj1 = tid + 256, r1 = jj1 >> 3, c1 = (jj1 & 7) * 8;
                *(short8*)&As[r1][c1] = pack8(ap10, ap11);
            }
            __syncthreads();
        }
    }

    // ---- epilogue 1: gelu + bias -> Hs (LDS) ----------------------------
    #pragma unroll
    for (int j = 0; j < 4; j++) {
        int col = w * 64 + j * 16 + cid;
        float bdv = bd[col];
        #pragma unroll
        for (int i = 0; i < 4; i++)
            #pragma unroll
            for (int r = 0; r < 4; r++)
                Hs[i * 16 + quad * 4 + r][col] = f2bs(gelu_exact(acc[i][j][r] + bdv));
    }
    // GEMM2's first __syncthreads orders Hs.

    // ---- GEMM2: K=256 ---------------------------------------------------
    f32x4 acc2[4][4];
    #pragma unroll
    for (int i = 0; i < 4; i++)
        #pragma unroll
        for (int j = 0; j < 4; j++) acc2[i][j] = (f32x4)(0.f);

    const short* Bsrc = eWB + (size_t)idc * A_DIM * A_DIM;
    for (int kt = 0; kt < A_DIM; kt += 64) {
        #pragma unroll
        for (int p = 0; p < 8; p++) {
            int jj = tid + p * 256;
            int r = jj >> 3;
            int cg = (((jj & 7) ^ (r & 7)) * 8);
            int cl = (jj & 7) * 8;
            gload_lds16(Bsrc + (size_t)r * A_DIM + kt + cg, &Bs[r][cl]);
        }
        __syncthreads();
        #pragma unroll
        for (int kk = 0; kk < 2; kk++) {
            short8 a[4], b[4];
            #pragma unroll
            for (int i = 0; i < 4; i++)
                a[i] = *(const short8*)&Hs[i * 16 + cid][kt + kk * 32 + quad * 8];
            #pragma unroll
            for (int j = 0; j < 4; j++)
                b[j] = *(const short8*)&Bs[w * 64 + j * 16 + cid]
                                         [(kk * 32 + quad * 8) ^ ((cid & 7) * 8)];
            #pragma unroll
            for (int i = 0; i < 4; i++)
                #pragma unroll
                for (int j = 0; j < 4; j++)
                    acc2[i][j] = __builtin_amdgcn_mfma_f32_16x16x32_bf16(
                        a[i], b[j], acc2[i][j], 0, 0, 0);
        }
        __syncthreads();
    }

    // ---- epilogue 2: + eb + emb (or H1 + emb when invalid) -> H2 --------
    #pragma unroll
    for (int j = 0; j < 4; j++) {
        int col = w * 64 + j * 16 + cid;
        float ebv = eb[idc * A_DIM + col];
        float ev  = emb[idc * A_DIM + col];
        #pragma unroll
        for (int i = 0; i < 4; i++)
            #pragma unroll
            for (int r = 0; r < 4; r++) {
                int rl = i * 16 + quad * 4 + r;
                float base;
                if (valid) base = acc2[i][j][r] + ebv;
                else       base = bs2f(Hs[rl][col]);
                H2[(size_t)(m0 + rl) * A_DIM + col] = f2bs(base + ev);
            }
    }
}

// ---------------------------------------------------------------------------
// up proj + bias + residual + LayerNorm, fused.
// v3: 512-thread blocks (8 waves x 128 cols, 16 rows) -> 128-VGPR budget
// (launch_bounds(512,4) = 2 blocks/CU) so the 64 per-wave B loads from L2 can
// pipeline deeply (round-2's 60-VGPR config had ~2-3 outstanding = the stall).
// One-shot padded panel stage (conflict-free, single barrier) kept.
// No X prefetch (proven regression); X loads batch-issue at epilogue start.
// ---------------------------------------------------------------------------
__global__ __launch_bounds__(512, 4) void k_up_ln(
    const short* __restrict__ H2, const short* __restrict__ WuB,
    const float* __restrict__ ub, const float* __restrict__ X,
    const float* __restrict__ gamma, const float* __restrict__ beta,
    float* __restrict__ out)
{
    __shared__ short As[16][264];
    __shared__ float redS[8][16], red2[8][16];
    __shared__ float muS[16], rsS[16];
    const int tid  = threadIdx.x;
    const int lane = tid & 63;
    const int w    = tid >> 6;            // 0..7
    const int quad = lane >> 4, cid = lane & 15;
    const int m0 = blockIdx.x * 16;
    const int nb = w * 128;               // wave's 128-col slice

    // one-shot panel stage: 16 rows x 256 cols bf16 = 8KB = 512 thr x 16B
    const int pr = tid >> 5, pc = (tid & 31) * 8;
    short8 pv = *(const short8*)(H2 + (size_t)(m0 + pr) * A_DIM + pc);
    *(short8*)&As[pr][pc] = pv;
    __syncthreads();                      // the only GEMM barrier

    f32x4 acc[8];
    #pragma unroll
    for (int j = 0; j < 8; j++) acc[j] = (f32x4)(0.f);

    const short* bbase = WuB + (size_t)(nb + cid) * A_DIM + quad * 8;

    #pragma unroll
    for (int kt = 0; kt < 4; kt++) {
        #pragma unroll
        for (int kk = 0; kk < 2; kk++) {
            short8 a0 = *(const short8*)&As[cid][kt * 64 + kk * 32 + quad * 8];
            #pragma unroll
            for (int j = 0; j < 8; j++) {
                short8 b = *(const short8*)(bbase + (size_t)(j * 16) * A_DIM
                                            + kt * 64 + kk * 32);
                acc[j] = __builtin_amdgcn_mfma_f32_16x16x32_bf16(a0, b, acc[j], 0, 0, 0);
            }
        }
    }

    // x = acc + up_b + residual; per-row partial sums over the wave's 128 cols
    float s1[4], s2[4];
    #pragma unroll
    for (int r = 0; r < 4; r++) { s1[r] = 0.f; s2[r] = 0.f; }
    #pragma unroll
    for (int j = 0; j < 8; j++) {
        int col = nb + j * 16 + cid;
        float ubv = ub[col];
        #pragma unroll
        for (int r = 0; r < 4; r++) {
            int row = m0 + quad * 4 + r;
            float x = acc[j][r] + ubv + X[(size_t)row * D_DIM + col];
            acc[j][r] = x;
            s1[r] += x;
            s2[r] += x * x;
        }
    }
    // reduce across the 16 lanes (cid) sharing a row
    #pragma unroll
    for (int r = 0; r < 4; r++) {
        float a = s1[r], b = s2[r];
        #pragma unroll
        for (int off = 1; off < 16; off <<= 1) {
            a += __shfl_xor(a, off, 64);
            b += __shfl_xor(b, off, 64);
        }
        if (cid == 0) {
            int rl = quad * 4 + r;        // 0..15: each wave covers all rows
            redS[w][rl] = a;
            red2[w][rl] = b;
        }
    }
    __syncthreads();
    if (tid < 16) {
        float S = 0.f, Q = 0.f;
        #pragma unroll
        for (int ww = 0; ww < 8; ww++) { S += redS[ww][tid]; Q += red2[ww][tid]; }
        float mu = S * (1.0f / 1024.0f);
        float var = Q * (1.0f / 1024.0f) - mu * mu;
        muS[tid] = mu;
        rsS[tid] = rsqrtf(var + 1e-5f);
    }
    __syncthreads();
    #pragma unroll
    for (int j = 0; j < 8; j++) {
        int col = nb + j * 16 + cid;
        float g = gamma[col], be = beta[col];
        #pragma unroll
        for (int r = 0; r < 4; r++) {
            int rl = quad * 4 + r;
            out[(size_t)(m0 + rl) * D_DIM + col] =
                (acc[j][r] - muS[rl]) * rsS[rl] * g + be;
        }
    }
}

extern "C" void kernel_launch(void* const* d_in, const int* in_sizes, int n_in,
                              void* d_out, int out_size, void* d_ws, size_t ws_size,
                              hipStream_t stream) {
    const float* hs  = (const float*)d_in[0];   // [32,1024,1024]
    const int*   did = (const int*)d_in[1];     // [32]
    const float* dW  = (const float*)d_in[2];   // [256,1024]
    const float* db  = (const float*)d_in[3];   // [256]
    const float* uW  = (const float*)d_in[4];   // [1024,256]
    const float* ub  = (const float*)d_in[5];   // [1024]
    const float* eW  = (const float*)d_in[6];   // [16,256,256]
    const float* ebv = (const float*)d_in[7];   // [16,256]
    const float* emb = (const float*)d_in[8];   // [16,256]
    const float* gam = (const float*)d_in[9];   // [1024]
    const float* bet = (const float*)d_in[10];  // [1024]
    float* out = (float*)d_out;

    char* ws = (char*)d_ws;
    short* WdB = (short*)(ws);                  // 512 KB
    short* WuB = (short*)(ws + (1u << 19));     // 512 KB
    short* eWB = (short*)(ws + (1u << 20));     // 2 MB
    short* H2  = (short*)(ws + (3u << 20));     // 16 MB (total 19 MB)

    k_cast_w     <<<768, 256, 0, stream>>>(dW, uW, eW, WdB, WuB, eWB);
    k_down_expert<<<512, 256, 0, stream>>>(hs, WdB, db, eWB, ebv, emb, did, H2);
    k_up_ln      <<<2048, 512, 0, stream>>>(H2, WuB, ub, hs, gam, bet, out);
}

// Round 4
// 337.274 us; speedup vs baseline: 1.1743x; 1.1743x over previous
//
#include <hip/hip_runtime.h>
#include <hip/hip_bf16.h>
#include <math.h>

#define D_DIM 1024
#define A_DIM 256
#define E_NUM 16

typedef __attribute__((ext_vector_type(8))) short short8;   // 8 bf16 (4 VGPRs)
typedef __attribute__((ext_vector_type(4))) float f32x4;    // MFMA acc

__device__ __forceinline__ short f2bs(float x) {
    __hip_bfloat16 h = __float2bfloat16(x);   // RNE
    return __builtin_bit_cast(short, h);
}
__device__ __forceinline__ float bs2f(short s) {
    __hip_bfloat16 h = __builtin_bit_cast(__hip_bfloat16, s);
    return __bfloat162float(h);
}
__device__ __forceinline__ float gelu_exact(float x) {
    return 0.5f * x * (1.0f + erff(x * 0.70710678118654752f));
}
// async global->LDS, 16B per lane; LDS dest must be wave-uniform base + lane*16
__device__ __forceinline__ void gload_lds16(const void* g, void* l) {
    __builtin_amdgcn_global_load_lds(
        (const __attribute__((address_space(1))) void*)g,
        (__attribute__((address_space(3))) void*)l, 16, 0, 0);
}
__device__ __forceinline__ short8 pack8(float4 u, float4 v) {
    short8 pk;
    pk[0] = f2bs(u.x); pk[1] = f2bs(u.y); pk[2] = f2bs(u.z); pk[3] = f2bs(u.w);
    pk[4] = f2bs(v.x); pk[5] = f2bs(v.y); pk[6] = f2bs(v.z); pk[7] = f2bs(v.w);
    return pk;
}

// ---------------------------------------------------------------------------
// cast: weights only. Wu is additionally TRANSPOSED into MFMA-fragment order:
// frag (jg = d>>4, p = k>>5) stored as 1KB contiguous block, lane-major:
//   WuT[ ((jg*8+p)*64 + lane)*8 ]  holds  Wu[d = jg*16 + (lane&15)]
//                                         [k = p*32 + (lane>>4)*8 .. +7]
// so k_up_ln's per-fragment wave load is one fully-coalesced 1KB burst.
// ---------------------------------------------------------------------------
__global__ __launch_bounds__(256) void k_cast_w(
    const float* __restrict__ Wd, const float* __restrict__ Wu,
    const float* __restrict__ eW,
    short* __restrict__ WdB, short* __restrict__ WuT, short* __restrict__ eWB)
{
    unsigned i = blockIdx.x * 256 + threadIdx.x;
    if (i < 131072) {
        const float4* s = (const float4*)eW;
        ((short8*)eWB)[i] = pack8(s[2 * (size_t)i], s[2 * (size_t)i + 1]);
    } else if (i < 163840) {
        unsigned j = i - 131072;
        const float4* s = (const float4*)Wd;
        ((short8*)WdB)[j] = pack8(s[2 * (size_t)j], s[2 * (size_t)j + 1]);
    } else {
        unsigned j = i - 163840;            // 0..32767 octet of Wu[1024][256]
        const float4* s = (const float4*)Wu;
        short8 v = pack8(s[2 * (size_t)j], s[2 * (size_t)j + 1]);
        unsigned d  = j >> 5;               // Wu row (output col)
        unsigned k0 = (j & 31) * 8;         // first k of this octet
        unsigned jg = d >> 4, cid = d & 15;
        unsigned p  = k0 >> 5, quad = (k0 >> 3) & 3;
        unsigned idx = ((jg * 8 + p) * 64 + quad * 16 + cid) * 8;
        *(short8*)(WuT + idx) = v;
    }
}

// ---------------------------------------------------------------------------
// Fused down-proj + GELU + expert GEMM (unchanged from round 3).
// ---------------------------------------------------------------------------
__global__ __launch_bounds__(256, 2) void k_down_expert(
    const float* __restrict__ X, const short* __restrict__ WdB,
    const float* __restrict__ bd, const short* __restrict__ eWB,
    const float* __restrict__ eb, const float* __restrict__ emb,
    const int* __restrict__ domain_id, short* __restrict__ H2)
{
    __shared__ short As[64][72];    // reg-staged: +8 pad legal
    __shared__ short Bs[256][64];   // gload_lds dest: linear; source pre-swizzled
    __shared__ short Hs[64][264];   // H1 panel, +8 pad
    const int tid  = threadIdx.x;
    const int lane = tid & 63;
    const int w    = tid >> 6;          // 0..3 = n-split
    const int quad = lane >> 4, cid = lane & 15;
    const int m0 = blockIdx.x * 64;

    const int samp = m0 >> 10;
    const int id = domain_id[samp];
    const bool valid = (id >= 0) && (id < E_NUM);
    const int idc = id < 0 ? 0 : (id > E_NUM - 1 ? E_NUM - 1 : id);

    f32x4 acc[4][4];
    #pragma unroll
    for (int i = 0; i < 4; i++)
        #pragma unroll
        for (int j = 0; j < 4; j++) acc[i][j] = (f32x4)(0.f);

    // ---- GEMM1 prologue: stage kt=0 -------------------------------------
    #pragma unroll
    for (int p = 0; p < 8; p++) {
        int jj = tid + p * 256;
        int r = jj >> 3;
        int cg = (((jj & 7) ^ (r & 7)) * 8);   // swizzled source col
        int cl = (jj & 7) * 8;                 // linear LDS col
        gload_lds16(WdB + (size_t)r * D_DIM + cg, &Bs[r][cl]);
    }
    #pragma unroll
    for (int p = 0; p < 2; p++) {
        int jj = tid + p * 256;
        int r = jj >> 3, c = (jj & 7) * 8;
        const float4* src = (const float4*)(X + (size_t)(m0 + r) * D_DIM + c);
        *(short8*)&As[r][c] = pack8(src[0], src[1]);
    }
    __syncthreads();

    // ---- GEMM1 main loop: K=1024, k-step 64 -----------------------------
    for (int kt = 0; kt < D_DIM; kt += 64) {
        const bool more = (kt + 64) < D_DIM;
        // T14 issue-early: next A tile into regs, fire before MFMA
        float4 ap00, ap01, ap10, ap11;
        if (more) {
            int jj0 = tid, r0 = jj0 >> 3, c0 = (jj0 & 7) * 8;
            const float4* s0 = (const float4*)(X + (size_t)(m0 + r0) * D_DIM + kt + 64 + c0);
            ap00 = s0[0]; ap01 = s0[1];
            int jj1 = tid + 256, r1 = jj1 >> 3, c1 = (jj1 & 7) * 8;
            const float4* s1 = (const float4*)(X + (size_t)(m0 + r1) * D_DIM + kt + 64 + c1);
            ap10 = s1[0]; ap11 = s1[1];
        }
        #pragma unroll
        for (int kk = 0; kk < 2; kk++) {
            short8 a[4], b[4];
            #pragma unroll
            for (int i = 0; i < 4; i++)
                a[i] = *(const short8*)&As[i * 16 + cid][kk * 32 + quad * 8];
            #pragma unroll
            for (int j = 0; j < 4; j++)
                b[j] = *(const short8*)&Bs[w * 64 + j * 16 + cid]
                                         [(kk * 32 + quad * 8) ^ ((cid & 7) * 8)];
            #pragma unroll
            for (int i = 0; i < 4; i++)
                #pragma unroll
                for (int j = 0; j < 4; j++)
                    acc[i][j] = __builtin_amdgcn_mfma_f32_16x16x32_bf16(
                        a[i], b[j], acc[i][j], 0, 0, 0);
        }
        __syncthreads();                 // all waves done reading stage kt
        if (more) {
            #pragma unroll
            for (int p = 0; p < 8; p++) {
                int jj = tid + p * 256;
                int r = jj >> 3;
                int cg = (((jj & 7) ^ (r & 7)) * 8);
                int cl = (jj & 7) * 8;
                gload_lds16(WdB + (size_t)r * D_DIM + kt + 64 + cg, &Bs[r][cl]);
            }
            {
                int jj0 = tid, r0 = jj0 >> 3, c0 = (jj0 & 7) * 8;
                *(short8*)&As[r0][c0] = pack8(ap00, ap01);
                int jj1 = tid + 256, r1 = jj1 >> 3, c1 = (jj1 & 7) * 8;
                *(short8*)&As[r1][c1] = pack8(ap10, ap11);
            }
            __syncthreads();
        }
    }

    // ---- epilogue 1: gelu + bias -> Hs (LDS) ----------------------------
    #pragma unroll
    for (int j = 0; j < 4; j++) {
        int col = w * 64 + j * 16 + cid;
        float bdv = bd[col];
        #pragma unroll
        for (int i = 0; i < 4; i++)
            #pragma unroll
            for (int r = 0; r < 4; r++)
                Hs[i * 16 + quad * 4 + r][col] = f2bs(gelu_exact(acc[i][j][r] + bdv));
    }
    // GEMM2's first __syncthreads orders Hs.

    // ---- GEMM2: K=256 ---------------------------------------------------
    f32x4 acc2[4][4];
    #pragma unroll
    for (int i = 0; i < 4; i++)
        #pragma unroll
        for (int j = 0; j < 4; j++) acc2[i][j] = (f32x4)(0.f);

    const short* Bsrc = eWB + (size_t)idc * A_DIM * A_DIM;
    for (int kt = 0; kt < A_DIM; kt += 64) {
        #pragma unroll
        for (int p = 0; p < 8; p++) {
            int jj = tid + p * 256;
            int r = jj >> 3;
            int cg = (((jj & 7) ^ (r & 7)) * 8);
            int cl = (jj & 7) * 8;
            gload_lds16(Bsrc + (size_t)r * A_DIM + kt + cg, &Bs[r][cl]);
        }
        __syncthreads();
        #pragma unroll
        for (int kk = 0; kk < 2; kk++) {
            short8 a[4], b[4];
            #pragma unroll
            for (int i = 0; i < 4; i++)
                a[i] = *(const short8*)&Hs[i * 16 + cid][kt + kk * 32 + quad * 8];
            #pragma unroll
            for (int j = 0; j < 4; j++)
                b[j] = *(const short8*)&Bs[w * 64 + j * 16 + cid]
                                         [(kk * 32 + quad * 8) ^ ((cid & 7) * 8)];
            #pragma unroll
            for (int i = 0; i < 4; i++)
                #pragma unroll
                for (int j = 0; j < 4; j++)
                    acc2[i][j] = __builtin_amdgcn_mfma_f32_16x16x32_bf16(
                        a[i], b[j], acc2[i][j], 0, 0, 0);
        }
        __syncthreads();
    }

    // ---- epilogue 2: + eb + emb (or H1 + emb when invalid) -> H2 --------
    #pragma unroll
    for (int j = 0; j < 4; j++) {
        int col = w * 64 + j * 16 + cid;
        float ebv = eb[idc * A_DIM + col];
        float ev  = emb[idc * A_DIM + col];
        #pragma unroll
        for (int i = 0; i < 4; i++)
            #pragma unroll
            for (int r = 0; r < 4; r++) {
                int rl = i * 16 + quad * 4 + r;
                float base;
                if (valid) base = acc2[i][j][r] + ebv;
                else       base = bs2f(Hs[rl][col]);
                H2[(size_t)(m0 + rl) * A_DIM + col] = f2bs(base + ev);
            }
    }
}

// ---------------------------------------------------------------------------
// up proj + bias + residual + LayerNorm, fused. v4:
//  - geometry back to the best-measured config: 1024 thr, 32 rows, 16 waves
//    (wave = 32r x 64c, acc[2][4]); one-shot padded panel, single barrier.
//  - B from WuT fragment layout: each fragment = ONE contiguous 1KB wave
//    load (lane*16B), full 128B lines, L2-hot across all blocks.
//  - explicit register double-buffer bcur/bnxt (static indices, rule #20
//    safe): 4 loads in flight guaranteed, issued before the MFMAs that
//    consume the previous group; no barriers in the k-loop so nothing
//    drains vmcnt.
// ---------------------------------------------------------------------------
__global__ __launch_bounds__(1024, 4) void k_up_ln(
    const short* __restrict__ H2, const short* __restrict__ WuT,
    const float* __restrict__ ub, const float* __restrict__ X,
    const float* __restrict__ gamma, const float* __restrict__ beta,
    float* __restrict__ out)
{
    __shared__ short As[32][264];
    __shared__ float redS[16][32], red2[16][32];
    __shared__ float muS[32], rsS[32];
    const int tid  = threadIdx.x;
    const int lane = tid & 63;
    const int w    = tid >> 6;            // 0..15
    const int quad = lane >> 4, cid = lane & 15;
    const int m0 = blockIdx.x * 32;
    const int nb = w * 64;                // wave's 64-col slice

    // one-shot panel stage: 32 x 256 bf16 = 16KB = 1024 thr x 16B
    const int pr = tid >> 5, pc = (tid & 31) * 8;
    short8 pv = *(const short8*)(H2 + (size_t)(m0 + pr) * A_DIM + pc);
    *(short8*)&As[pr][pc] = pv;
    __syncthreads();                      // the only GEMM barrier

    f32x4 acc[2][4];
    #pragma unroll
    for (int mf = 0; mf < 2; mf++)
        #pragma unroll
        for (int j = 0; j < 4; j++) acc[mf][j] = (f32x4)(0.f);

    // wave's fragment base: frags (w*4 + j)*8 + p, lane-major 1KB each
    const short* bt = WuT + ((size_t)w * 32) * 512 + (size_t)lane * 8;

    short8 bcur[4], bnxt[4];
    #pragma unroll
    for (int j = 0; j < 4; j++)
        bcur[j] = *(const short8*)(bt + (size_t)(j * 8) * 512);

    #pragma unroll
    for (int p = 0; p < 8; p++) {
        if (p < 7) {
            #pragma unroll
            for (int j = 0; j < 4; j++)
                bnxt[j] = *(const short8*)(bt + (size_t)(j * 8 + p + 1) * 512);
        }
        short8 a0 = *(const short8*)&As[cid][p * 32 + quad * 8];
        short8 a1 = *(const short8*)&As[16 + cid][p * 32 + quad * 8];
        #pragma unroll
        for (int j = 0; j < 4; j++) {
            acc[0][j] = __builtin_amdgcn_mfma_f32_16x16x32_bf16(a0, bcur[j], acc[0][j], 0, 0, 0);
            acc[1][j] = __builtin_amdgcn_mfma_f32_16x16x32_bf16(a1, bcur[j], acc[1][j], 0, 0, 0);
        }
        if (p < 7) {
            #pragma unroll
            for (int j = 0; j < 4; j++) bcur[j] = bnxt[j];
        }
    }

    // x = acc + up_b + residual; per-row partial sums
    float s1[2][4], s2[2][4];
    #pragma unroll
    for (int mf = 0; mf < 2; mf++)
        #pragma unroll
        for (int r = 0; r < 4; r++) { s1[mf][r] = 0.f; s2[mf][r] = 0.f; }
    #pragma unroll
    for (int j = 0; j < 4; j++) {
        int col = nb + j * 16 + cid;
        float ubv = ub[col];
        #pragma unroll
        for (int mf = 0; mf < 2; mf++)
            #pragma unroll
            for (int r = 0; r < 4; r++) {
                int row = m0 + mf * 16 + quad * 4 + r;
                float x = acc[mf][j][r] + ubv + X[(size_t)row * D_DIM + col];
                acc[mf][j][r] = x;
                s1[mf][r] += x;
                s2[mf][r] += x * x;
            }
    }
    // reduce across the 16 lanes (cid) sharing a row
    #pragma unroll
    for (int mf = 0; mf < 2; mf++)
        #pragma unroll
        for (int r = 0; r < 4; r++) {
            float a = s1[mf][r], b = s2[mf][r];
            #pragma unroll
            for (int off = 1; off < 16; off <<= 1) {
                a += __shfl_xor(a, off, 64);
                b += __shfl_xor(b, off, 64);
            }
            if (cid == 0) {
                int rl = mf * 16 + quad * 4 + r;
                redS[w][rl] = a;
                red2[w][rl] = b;
            }
        }
    __syncthreads();
    if (tid < 32) {
        float S = 0.f, Q = 0.f;
        #pragma unroll
        for (int ww = 0; ww < 16; ww++) { S += redS[ww][tid]; Q += red2[ww][tid]; }
        float mu = S * (1.0f / 1024.0f);
        float var = Q * (1.0f / 1024.0f) - mu * mu;
        muS[tid] = mu;
        rsS[tid] = rsqrtf(var + 1e-5f);
    }
    __syncthreads();
    #pragma unroll
    for (int j = 0; j < 4; j++) {
        int col = nb + j * 16 + cid;
        float g = gamma[col], be = beta[col];
        #pragma unroll
        for (int mf = 0; mf < 2; mf++)
            #pragma unroll
            for (int r = 0; r < 4; r++) {
                int rl = mf * 16 + quad * 4 + r;
                out[(size_t)(m0 + rl) * D_DIM + col] =
                    (acc[mf][j][r] - muS[rl]) * rsS[rl] * g + be;
            }
    }
}

extern "C" void kernel_launch(void* const* d_in, const int* in_sizes, int n_in,
                              void* d_out, int out_size, void* d_ws, size_t ws_size,
                              hipStream_t stream) {
    const float* hs  = (const float*)d_in[0];   // [32,1024,1024]
    const int*   did = (const int*)d_in[1];     // [32]
    const float* dW  = (const float*)d_in[2];   // [256,1024]
    const float* db  = (const float*)d_in[3];   // [256]
    const float* uW  = (const float*)d_in[4];   // [1024,256]
    const float* ub  = (const float*)d_in[5];   // [1024]
    const float* eW  = (const float*)d_in[6];   // [16,256,256]
    const float* ebv = (const float*)d_in[7];   // [16,256]
    const float* emb = (const float*)d_in[8];   // [16,256]
    const float* gam = (const float*)d_in[9];   // [1024]
    const float* bet = (const float*)d_in[10];  // [1024]
    float* out = (float*)d_out;

    char* ws = (char*)d_ws;
    short* WdB = (short*)(ws);                  // 512 KB
    short* WuT = (short*)(ws + (1u << 19));     // 512 KB (fragment layout)
    short* eWB = (short*)(ws + (1u << 20));     // 2 MB
    short* H2  = (short*)(ws + (3u << 20));     // 16 MB (total 19 MB)

    k_cast_w     <<<768, 256, 0, stream>>>(dW, uW, eW, WdB, WuT, eWB);
    k_down_expert<<<512, 256, 0, stream>>>(hs, WdB, db, eWB, ebv, emb, did, H2);
    k_up_ln      <<<1024, 1024, 0, stream>>>(H2, WuT, ub, hs, gam, bet, out);
}